// Round 1
// baseline (182.343 us; speedup 1.0000x reference)
//
#include <hip/hip_runtime.h>
#include <hip/hip_bf16.h>
#include <stdint.h>

#define M_DIM 8192
#define N_DIM 8192
#define D_DIM 512
#define BM 128
#define BN 128
#define BK 32
#define KITERS (D_DIM / BK)   // 16

typedef __bf16 bf16x8 __attribute__((ext_vector_type(8)));
typedef float f32x4 __attribute__((ext_vector_type(4)));

__device__ inline void gload_lds16(const void* g, void* l) {
  __builtin_amdgcn_global_load_lds(
      (const __attribute__((address_space(1))) void*)g,
      (__attribute__((address_space(3))) void*)l, 16, 0, 0);
}

// One wave (64 threads) per row: fp32 -> bf16 convert + squared-norm.
__global__ __launch_bounds__(64) void prep_kernel(
    const float* __restrict__ x, const float* __restrict__ xt,
    __hip_bfloat16* __restrict__ xb, __hip_bfloat16* __restrict__ xtb,
    float* __restrict__ xx, float* __restrict__ yy) {
  int row = blockIdx.x;
  const float* src;
  __hip_bfloat16* dst;
  float* nrm;
  if (row < M_DIM) {
    src = x + (size_t)row * D_DIM;
    dst = xb + (size_t)row * D_DIM;
    nrm = xx + row;
  } else {
    int r = row - M_DIM;
    src = xt + (size_t)r * D_DIM;
    dst = xtb + (size_t)r * D_DIM;
    nrm = yy + r;
  }
  int lane = threadIdx.x;  // 0..63, covers 512 elements as 8 per lane
  const float4* s4 = (const float4*)src;
  float4 a = s4[lane * 2];
  float4 b = s4[lane * 2 + 1];
  float nv = a.x * a.x + a.y * a.y + a.z * a.z + a.w * a.w +
             b.x * b.x + b.y * b.y + b.z * b.z + b.w * b.w;
  union {
    __hip_bfloat16 h[8];
    int4 v;
  } u;
  u.h[0] = __float2bfloat16(a.x);
  u.h[1] = __float2bfloat16(a.y);
  u.h[2] = __float2bfloat16(a.z);
  u.h[3] = __float2bfloat16(a.w);
  u.h[4] = __float2bfloat16(b.x);
  u.h[5] = __float2bfloat16(b.y);
  u.h[6] = __float2bfloat16(b.z);
  u.h[7] = __float2bfloat16(b.w);
  ((int4*)dst)[lane] = u.v;
#pragma unroll
  for (int off = 32; off; off >>= 1) nv += __shfl_xor(nv, off, 64);
  if (lane == 0) *nrm = nv;
}

__global__ void init_out(float* __restrict__ out, const float* __restrict__ bias) {
  int i = blockIdx.x * blockDim.x + threadIdx.x;
  if (i < M_DIM) out[i] = bias[0];
}

// 128x128 tile, BK=32, 4 waves (2x2), each wave 4x4 MFMA 16x16x32 tiles.
// Fused epilogue: k = exp(-g*max(xx+yy-2*s,0)) * w[n], reduce over n, atomicAdd.
__global__ __launch_bounds__(256) void rbf_gemm(
    const __hip_bfloat16* __restrict__ A,  // [M][D] bf16
    const __hip_bfloat16* __restrict__ B,  // [N][D] bf16
    const float* __restrict__ xx, const float* __restrict__ yy,
    const float* __restrict__ w, const float* __restrict__ gamma,
    float* __restrict__ out) {
  __shared__ __hip_bfloat16 As[BM * BK];  // 8 KB, row-major [BM][BK]
  __shared__ __hip_bfloat16 Bs[BN * BK];  // 8 KB
  __shared__ float rowsum[BM];

  const int tid = threadIdx.x;
  const int lane = tid & 63;
  const int wid = tid >> 6;
  const int wm = wid >> 1;  // 0..1
  const int wn = wid & 1;   // 0..1
  const int bm = blockIdx.y, bn = blockIdx.x;

  if (tid < BM) rowsum[tid] = 0.0f;

  const size_t a_base = (size_t)bm * BM * D_DIM;
  const size_t b_base = (size_t)bn * BN * D_DIM;

  f32x4 acc[4][4];
  const f32x4 zero = {0.f, 0.f, 0.f, 0.f};
#pragma unroll
  for (int i = 0; i < 4; i++)
#pragma unroll
    for (int j = 0; j < 4; j++) acc[i][j] = zero;

  const int frow = lane & 15;  // fragment row/col within 16x16
  const int fk8 = lane >> 4;   // which 8-element k-chunk (0..3)

  for (int kt = 0; kt < KITERS; ++kt) {
    __syncthreads();  // previous tile fully consumed
    const int k0 = kt * BK;
    // Stage A,B tiles: slot = issue*256 + tid; 16B per slot; row = slot>>2.
#pragma unroll
    for (int issue = 0; issue < 2; ++issue) {
      int slot = issue * 256 + tid;
      int row = slot >> 2, c8 = slot & 3;
      gload_lds16(A + a_base + (size_t)row * D_DIM + k0 + c8 * 8,
                  (char*)As + (size_t)(issue * 256 + wid * 64) * 16);
      gload_lds16(B + b_base + (size_t)row * D_DIM + k0 + c8 * 8,
                  (char*)Bs + (size_t)(issue * 256 + wid * 64) * 16);
    }
    __syncthreads();  // staged (compiler drains vmcnt before barrier)

    bf16x8 af[4], bfr[4];
#pragma unroll
    for (int i = 0; i < 4; i++) {
      int row = wm * 64 + i * 16 + frow;
      af[i] = *(const bf16x8*)((const char*)As + row * (BK * 2) + fk8 * 16);
    }
#pragma unroll
    for (int j = 0; j < 4; j++) {
      int col = wn * 64 + j * 16 + frow;
      bfr[j] = *(const bf16x8*)((const char*)Bs + col * (BK * 2) + fk8 * 16);
    }
#pragma unroll
    for (int i = 0; i < 4; i++)
#pragma unroll
      for (int j = 0; j < 4; j++)
        acc[i][j] =
            __builtin_amdgcn_mfma_f32_16x16x32_bf16(af[i], bfr[j], acc[i][j], 0, 0, 0);
  }

  // Epilogue. C layout: col = lane&15, row = (lane>>4)*4 + reg.
  const float g = gamma[0];
  float yv[4], wv[4];
#pragma unroll
  for (int j = 0; j < 4; j++) {
    int n = bn * BN + wn * 64 + j * 16 + frow;
    yv[j] = yy[n];
    wv[j] = w[n];
  }
#pragma unroll
  for (int i = 0; i < 4; i++) {
#pragma unroll
    for (int r = 0; r < 4; r++) {
      int mrow = wm * 64 + i * 16 + fk8 * 4 + r;  // local row in [0,128)
      float xv = xx[bm * BM + mrow];
      float s = 0.f;
#pragma unroll
      for (int j = 0; j < 4; j++) {
        float v = acc[i][j][r];
        float sq = fmaxf(xv + yv[j] - 2.0f * v, 0.0f);
        s += wv[j] * __expf(-g * sq);
      }
      // reduce the 16 cols held across the 16-lane group
      s += __shfl_xor(s, 1, 64);
      s += __shfl_xor(s, 2, 64);
      s += __shfl_xor(s, 4, 64);
      s += __shfl_xor(s, 8, 64);
      if (frow == 0) atomicAdd(&rowsum[mrow], s);
    }
  }
  __syncthreads();
  if (tid < BM) atomicAdd(&out[bm * BM + tid], rowsum[tid]);
}

extern "C" void kernel_launch(void* const* d_in, const int* in_sizes, int n_in,
                              void* d_out, int out_size, void* d_ws, size_t ws_size,
                              hipStream_t stream) {
  const float* x = (const float*)d_in[0];       // [8192,512]
  const float* xt = (const float*)d_in[1];      // [8192,512]
  const float* gamma = (const float*)d_in[2];   // [1]
  const float* weight = (const float*)d_in[3];  // [8192,1]
  const float* bias = (const float*)d_in[4];    // [1]
  float* out = (float*)d_out;                   // [8192]

  char* ws = (char*)d_ws;
  __hip_bfloat16* xb = (__hip_bfloat16*)ws;                                   // 8 MB
  __hip_bfloat16* xtb = (__hip_bfloat16*)(ws + (size_t)8 * 1024 * 1024);      // 8 MB
  float* xx = (float*)(ws + (size_t)16 * 1024 * 1024);                        // 32 KB
  float* yy = (float*)(ws + (size_t)16 * 1024 * 1024 + 32 * 1024);            // 32 KB

  prep_kernel<<<M_DIM + N_DIM, 64, 0, stream>>>(x, xt, xb, xtb, xx, yy);
  init_out<<<(M_DIM + 255) / 256, 256, 0, stream>>>(out, bias);
  dim3 grid(N_DIM / BN, M_DIM / BM);
  rbf_gemm<<<grid, 256, 0, stream>>>(xb, xtb, xx, yy, weight, gamma, out);
}